// Round 1
// baseline (195.641 us; speedup 1.0000x reference)
//
#include <hip/hip_runtime.h>

#define VOCAB 100000
#define DIM 128
#define BATCH 65536
#define N_NEG 10

#define BLOCKS 2048            // 4 waves/block * 2 elems/wave = 8 elems/iter/block
#define ELEMS_PER_PASS (BLOCKS * 8)   // 16384
#define N_ITERS (BATCH / ELEMS_PER_PASS) // 4

__device__ __forceinline__ float softplus_f(float x) {
    // log(1+exp(x)) stable
    return fmaxf(x, 0.0f) + log1pf(__expf(-fabsf(x)));
}

__global__ void zero_out_kernel(float* out) { out[0] = 0.0f; }

__global__ __launch_bounds__(256) void skipgram_loss_kernel(
    const int* __restrict__ pos_u,
    const int* __restrict__ pos_v,
    const int* __restrict__ neg_v,
    const float4* __restrict__ u_weight,   // VOCAB x 32 float4
    const float4* __restrict__ v_weight,   // VOCAB x 32 float4
    float* __restrict__ out)
{
    const int tid  = threadIdx.x;
    const int lane = tid & 63;
    const int wave = tid >> 6;      // 0..3
    const int half = lane >> 5;     // 0 or 1
    const int sub  = lane & 31;     // 0..31 -> float4 index within 128-float row

    // global half-wave id: handles one batch element per iteration
    const int hw = (blockIdx.x * 4 + wave) * 2 + half;

    float acc = 0.0f;   // per-lane accumulated loss (redundant across the 32-lane half)

    #pragma unroll
    for (int it = 0; it < N_ITERS; ++it) {
        const int b = hw + it * ELEMS_PER_PASS;

        const int iu = pos_u[b];
        const int iv = pos_v[b];

        const float4 u4 = u_weight[iu * 32 + sub];
        const float4 v4 = v_weight[iv * 32 + sub];
        float p = u4.x * v4.x + u4.y * v4.y + u4.z * v4.z + u4.w * v4.w;

        float nd[N_NEG];
        #pragma unroll
        for (int n = 0; n < N_NEG; ++n) {
            const int idx = neg_v[b * N_NEG + n];
            const float4 w4 = v_weight[idx * 32 + sub];
            nd[n] = u4.x * w4.x + u4.y * w4.y + u4.z * w4.z + u4.w * w4.w;
        }

        // reduce the 11 dots across the 32-lane half (xor masks 1..16 stay in-half)
        #pragma unroll
        for (int m = 1; m < 32; m <<= 1) {
            p += __shfl_xor(p, m, 64);
            #pragma unroll
            for (int n = 0; n < N_NEG; ++n) nd[n] += __shfl_xor(nd[n], m, 64);
        }

        float s = fminf(fmaxf(p, -10.0f), 10.0f);
        float loss = softplus_f(-s);          // -log_sigmoid(s)
        #pragma unroll
        for (int n = 0; n < N_NEG; ++n)
            loss -= softplus_f(nd[n]);        // + log_sigmoid(-d) == -softplus(d)

        acc += loss;
    }

    // block reduction: one value per half-wave
    __shared__ float smem[8];
    if (sub == 0) smem[wave * 2 + half] = acc;
    __syncthreads();
    if (tid == 0) {
        float sum = 0.0f;
        #pragma unroll
        for (int i = 0; i < 8; ++i) sum += smem[i];
        atomicAdd(out, sum * (1.0f / (float)BATCH));
    }
}

extern "C" void kernel_launch(void* const* d_in, const int* in_sizes, int n_in,
                              void* d_out, int out_size, void* d_ws, size_t ws_size,
                              hipStream_t stream) {
    const int*   pos_u    = (const int*)d_in[0];
    const int*   pos_v    = (const int*)d_in[1];
    const int*   neg_v    = (const int*)d_in[2];
    const float4* u_weight = (const float4*)d_in[3];
    const float4* v_weight = (const float4*)d_in[4];
    float* out = (float*)d_out;

    zero_out_kernel<<<1, 1, 0, stream>>>(out);
    skipgram_loss_kernel<<<BLOCKS, 256, 0, stream>>>(
        pos_u, pos_v, neg_v, u_weight, v_weight, out);
}

// Round 3
// 160.946 us; speedup vs baseline: 1.2156x; 1.2156x over previous
//
#include <hip/hip_runtime.h>

#define VOCAB 100000
#define DIM 128
#define BATCH 65536
#define N_NEG 10

// 8 lanes/element, 8 elements/wave, 4 waves/block => 32 elements/block
#define BLOCKS (BATCH / 32)   // 2048

__device__ __forceinline__ float softplus_f(float x) {
    // log(1+exp(x)), stable
    return fmaxf(x, 0.0f) + log1pf(__expf(-fabsf(x)));
}

__device__ __forceinline__ float dot4(float4 a, float4 b) {
    return a.x * b.x + a.y * b.y + a.z * b.z + a.w * b.w;
}

__global__ void zero_out_kernel(float* out) { out[0] = 0.0f; }

__global__ __launch_bounds__(256) void skipgram_loss_kernel(
    const int* __restrict__ pos_u,
    const int* __restrict__ pos_v,
    const int* __restrict__ neg_v,
    const float4* __restrict__ u_weight,   // VOCAB x 32 float4
    const float4* __restrict__ v_weight,   // VOCAB x 32 float4
    float* __restrict__ out)
{
    const int tid  = threadIdx.x;
    const int lane = tid & 63;
    const int wave = tid >> 6;      // 0..3
    const int sub  = lane & 7;      // 0..7 within the 8-lane group
    const int grp  = lane >> 3;     // 0..7: group within wave

    const int b = (blockIdx.x * 4 + wave) * 8 + grp;   // one batch element per group

    const int iu = pos_u[b];
    const int iv = pos_v[b];

    // u row: 4 chunks; chunk c = float4s [c*8 .. c*8+7] -> each inst 128B-coalesced/group
    const float4* __restrict__ urow = u_weight + iu * 32;
    float4 u0 = urow[0 * 8 + sub];
    float4 u1 = urow[1 * 8 + sub];
    float4 u2 = urow[2 * 8 + sub];
    float4 u3 = urow[3 * 8 + sub];

    const float4* __restrict__ vrow = v_weight + iv * 32;
    float p = dot4(u0, vrow[0 * 8 + sub]) + dot4(u1, vrow[1 * 8 + sub])
            + dot4(u2, vrow[2 * 8 + sub]) + dot4(u3, vrow[3 * 8 + sub]);

    float nd[N_NEG];
    #pragma unroll
    for (int n = 0; n < N_NEG; ++n) {
        const int idx = neg_v[b * N_NEG + n];
        const float4* __restrict__ wrow = v_weight + idx * 32;
        nd[n] = dot4(u0, wrow[0 * 8 + sub]) + dot4(u1, wrow[1 * 8 + sub])
              + dot4(u2, wrow[2 * 8 + sub]) + dot4(u3, wrow[3 * 8 + sub]);
    }

    // reduce the 11 dots across the 8-lane group (3 levels)
    #pragma unroll
    for (int m = 1; m < 8; m <<= 1) {
        p += __shfl_xor(p, m, 64);
        #pragma unroll
        for (int n = 0; n < N_NEG; ++n) nd[n] += __shfl_xor(nd[n], m, 64);
    }

    float s = fminf(fmaxf(p, -10.0f), 10.0f);
    float loss = softplus_f(-s);              // -log_sigmoid(s)
    #pragma unroll
    for (int n = 0; n < N_NEG; ++n)
        loss -= softplus_f(nd[n]);            // + log_sigmoid(-d) == -softplus(d)

    // Each 8-lane group holds its own loss (identical across the group's lanes).
    // Butterfly over masks 8,16,32 pairs lanes of DIFFERENT groups -> every lane
    // ends with the sum of the 8 distinct group losses, each counted exactly once.
    #pragma unroll
    for (int m = 8; m < 64; m <<= 1) loss += __shfl_xor(loss, m, 64);

    __shared__ float smem[4];
    if (lane == 0) smem[wave] = loss;
    __syncthreads();
    if (tid == 0) {
        atomicAdd(out, (smem[0] + smem[1] + smem[2] + smem[3]) * (1.0f / (float)BATCH));
    }
}

extern "C" void kernel_launch(void* const* d_in, const int* in_sizes, int n_in,
                              void* d_out, int out_size, void* d_ws, size_t ws_size,
                              hipStream_t stream) {
    const int*    pos_u    = (const int*)d_in[0];
    const int*    pos_v    = (const int*)d_in[1];
    const int*    neg_v    = (const int*)d_in[2];
    const float4* u_weight = (const float4*)d_in[3];
    const float4* v_weight = (const float4*)d_in[4];
    float* out = (float*)d_out;

    zero_out_kernel<<<1, 1, 0, stream>>>(out);
    skipgram_loss_kernel<<<BLOCKS, 256, 0, stream>>>(
        pos_u, pos_v, neg_v, u_weight, v_weight, out);
}